// Round 5
// baseline (412.936 us; speedup 1.0000x reference)
//
#include <hip/hip_runtime.h>
#include <hip/hip_bf16.h>

// EdgeProposer: probs/directions/relations heads over gathered belief pairs.
// f32 in / f32 out. R4 analysis: SIMD MFMA-busy ~5%; bottleneck = per-wave
// WT B-operand L2 line traffic (full 0.94MB WT re-read per 64-row block) +
// 4-way LDS read conflicts (LDA=72). R5: 128-row blocks (WT traffic per
// FLOP halved, 240 MFMA/wave/k0 between barriers), fragment-major LDS
// layout As2[seg][kk2][rt][lane][8] (A-frag reads lane*16B, conflict-free),
// paired-thread gathers (2 threads cover one 64B line). Epilogue in two
// 64-row halves so acts fits the As2 alias region.

#define DD 512
#define K3 1536
#define ROWS 128
#define LDACT 328   // 320 + 8 pad
#define LDH 72

typedef short bf16x8 __attribute__((ext_vector_type(8)));
typedef float f32x4 __attribute__((ext_vector_type(4)));

__device__ inline float b2f(short s) {
    union { float f; unsigned u; } v;
    v.u = ((unsigned)(unsigned short)s) << 16;
    return v.f;
}
__device__ inline short f2b(float f) {   // RNE
    union { float fl; unsigned u; } v;
    v.fl = f;
    unsigned x = v.u;
    unsigned r = x + 0x7fffu + ((x >> 16) & 1u);
    return (short)(r >> 16);
}
__device__ inline short babsdiff(short a, short b) {
    union { float f; unsigned u; } v;
    v.f = b2f(a) - b2f(b);
    return (short)((v.u & 0x7fffffffu) >> 16);
}

// As2 fragment-major index: [seg][kk2][rt][lane][8] (shorts)
__device__ __forceinline__ int sidx(int seg, int kk2, int rt, int lane) {
    return (((seg * 2 + kk2) * 8 + rt) * 64 + lane) * 8;
}

// ---- workspace layout (shorts) ----
#define WT_ELEMS (320 * 1536)
#define P2T_OFF WT_ELEMS
#define R2T_OFF (WT_ELEMS + 64 * 128)
#define PREP_TOT (WT_ELEMS + 2 * 64 * 128)
#define BEL_ELEMS (8192 * 512)
#define BEL_OFF PREP_TOT

__global__ void prep_kernel(const float* __restrict__ pw1,
                            const float* __restrict__ dw1,
                            const float* __restrict__ rw1,
                            const float* __restrict__ pw2,
                            const float* __restrict__ rw2,
                            const float* __restrict__ beliefs,
                            short* __restrict__ ws, int total) {
    int i = blockIdx.x * 256 + threadIdx.x;
    if (i >= total) return;
    if (i < WT_ELEMS) {
        int n = i / K3, k = i - n * K3;
        float v;
        if (n < 128)      v = pw1[k * 128 + n];
        else if (n < 192) v = dw1[k * 64 + (n - 128)];
        else              v = rw1[k * 128 + (n - 192)];
        ws[i] = f2b(v);
    } else if (i < R2T_OFF) {
        int j = i - P2T_OFF;
        int n = j >> 7, k = j & 127;
        ws[i] = f2b(pw2[k * 64 + n]);
    } else if (i < PREP_TOT) {
        int j = i - R2T_OFF;
        int n = j >> 7, k = j & 127;
        ws[i] = f2b(rw2[k * 64 + n]);
    } else {
        ws[i] = f2b(beliefs[i - BEL_OFF]);
    }
}

// ---- main fused kernel: 128 pairs per block, 256 threads (4 waves) ----
template<bool BF>
__global__ __launch_bounds__(256, 2) void edge_main(
    const float* __restrict__ beliefs, const short* __restrict__ bel16,
    const int* __restrict__ src_idx, const int* __restrict__ tgt_idx,
    const float* __restrict__ pb1, const float* __restrict__ db1,
    const float* __restrict__ rb1,
    const float* __restrict__ pb2, const float* __restrict__ pw3,
    const float* __restrict__ pb3,
    const float* __restrict__ dw2, const float* __restrict__ db2,
    const float* __restrict__ rb2,
    const short* __restrict__ WT, const short* __restrict__ pw2T,
    const short* __restrict__ rw2T,
    float* __restrict__ out, int N)
{
    // As2 (K-loop) and acts (epilogue) alias
    __shared__ __align__(16) char smem_u[49152];            // As2: 3*2*8*64*8*2 B
    __shared__ __align__(16) short h2s[64][LDH];            // 9216 B
    __shared__ int sIdx[ROWS], tIdx[ROWS];

    short* As2 = (short*)smem_u;
    short (*acts)[LDACT] = (short (*)[LDACT])smem_u;        // 64*328*2 = 41984 B

    const int t = threadIdx.x;
    const int r0 = blockIdx.x * ROWS;
    const int w = t >> 6, lane = t & 63, q = lane >> 4, ln = lane & 15;

    if (t < ROWS) sIdx[t] = src_idx[r0 + t] * DD;
    else tIdx[t - ROWS] = tgt_idx[r0 + t - ROWS] * DD;
    __syncthreads();

    f32x4 acc[5][8];
#pragma unroll
    for (int ct = 0; ct < 5; ct++)
#pragma unroll
        for (int rt = 0; rt < 8; rt++) acc[ct][rt] = (f32x4)(0.f);

    // staging role: thread pair (t, t^1) covers one row x 64 k (one 64B line
    // per source in bf16). kk2w = which 32-k half this thread stages.
    const int rrow = t >> 1, kk2w = t & 1;
    const int rtw = rrow >> 4, lnw = rrow & 15;
    const int cb32 = kk2w * 32;
    const int srow = sIdx[rrow], trow = tIdx[rrow];

    bf16x8 pS[4], pT[4];                // BF gather prefetch (32 VGPRs)
    float4 fS[8], fT[8];                // f32 fallback (64 VGPRs)

#define ISSUE_GATHER(k)                                                       \
    do {                                                                      \
        if constexpr (BF) {                                                   \
            const bf16x8* ps_ = (const bf16x8*)(bel16 + srow + (k) + cb32);   \
            const bf16x8* pt_ = (const bf16x8*)(bel16 + trow + (k) + cb32);   \
            pS[0]=ps_[0]; pS[1]=ps_[1]; pS[2]=ps_[2]; pS[3]=ps_[3];           \
            pT[0]=pt_[0]; pT[1]=pt_[1]; pT[2]=pt_[2]; pT[3]=pt_[3];           \
        } else {                                                              \
            const float4* ps_ = (const float4*)(beliefs + srow + (k) + cb32); \
            const float4* pt_ = (const float4*)(beliefs + trow + (k) + cb32); \
            _Pragma("unroll")                                                 \
            for (int c = 0; c < 8; c++) { fS[c] = ps_[c]; fT[c] = pt_[c]; }   \
        }                                                                     \
    } while (0)

    ISSUE_GATHER(0);

    for (int k0 = 0; k0 < DD; k0 += 64) {
        // ---- stage src / tgt / |src-tgt| into fragment-major LDS ----
        if constexpr (BF) {
#pragma unroll
            for (int c = 0; c < 4; c++) {
                bf16x8 pa;
#pragma unroll
                for (int j = 0; j < 8; j++) pa[j] = babsdiff(pS[c][j], pT[c][j]);
                int l16 = c * 16 + lnw;
                *(bf16x8*)&As2[sidx(0, kk2w, rtw, l16)] = pS[c];
                *(bf16x8*)&As2[sidx(1, kk2w, rtw, l16)] = pT[c];
                *(bf16x8*)&As2[sidx(2, kk2w, rtw, l16)] = pa;
            }
        } else {
#pragma unroll
            for (int c = 0; c < 4; c++) {
                bf16x8 sb, tb, ab;
#pragma unroll
                for (int h = 0; h < 2; h++) {
                    float ss[4] = {fS[c*2+h].x, fS[c*2+h].y, fS[c*2+h].z, fS[c*2+h].w};
                    float tt[4] = {fT[c*2+h].x, fT[c*2+h].y, fT[c*2+h].z, fT[c*2+h].w};
#pragma unroll
                    for (int e = 0; e < 4; e++) {
                        int j = h * 4 + e;
                        sb[j] = f2b(ss[e]);
                        tb[j] = f2b(tt[e]);
                        ab[j] = f2b(fabsf(ss[e] - tt[e]));
                    }
                }
                int l16 = c * 16 + lnw;
                *(bf16x8*)&As2[sidx(0, kk2w, rtw, l16)] = sb;
                *(bf16x8*)&As2[sidx(1, kk2w, rtw, l16)] = tb;
                *(bf16x8*)&As2[sidx(2, kk2w, rtw, l16)] = ab;
            }
        }
        __syncthreads();

        // next gather: drains at the barrier below, hidden under 240 MFMA
        if (k0 + 64 < DD) ISSUE_GATHER(k0 + 64);

        // ---- MFMA phase: 2 kk2 x 3 seg x (8 ds_read + 5 WT loads + 40 MFMA)
#pragma unroll
        for (int kk2 = 0; kk2 < 2; kk2++) {
#pragma unroll
            for (int seg = 0; seg < 3; seg++) {
                bf16x8 af[8];
#pragma unroll
                for (int rt = 0; rt < 8; rt++)
                    af[rt] = *(const bf16x8*)&As2[sidx(seg, kk2, rt, lane)];
#pragma unroll
                for (int ct = 0; ct < 5; ct++) {
                    int col = w * 80 + ct * 16 + ln;
                    bf16x8 bfr = *(const bf16x8*)(WT + (size_t)col * K3 +
                                                  seg * DD + k0 + kk2 * 32 + q * 8);
#pragma unroll
                    for (int rt = 0; rt < 8; rt++)
                        acc[ct][rt] = __builtin_amdgcn_mfma_f32_16x16x32_bf16(
                            af[rt], bfr, acc[ct][rt], 0, 0, 0);
                }
            }
        }
        __syncthreads();
    }

    // ---- epilogue: two 64-row halves (acts LDS = 64 rows) ----
#pragma unroll
    for (int h = 0; h < 2; h++) {
        // phase B: bias + relu -> acts[64][320]. C/D: col=lane&15, row=q*4+reg.
#pragma unroll
        for (int ct = 0; ct < 5; ct++) {
            int col = w * 80 + ct * 16 + ln;
            float bias = (col < 128) ? pb1[col]
                       : (col < 192) ? db1[col - 128]
                                     : rb1[col - 192];
#pragma unroll
            for (int rt4 = 0; rt4 < 4; rt4++)
#pragma unroll
                for (int i = 0; i < 4; i++) {
                    int lrow = rt4 * 16 + q * 4 + i;
                    float v = acc[ct][h * 4 + rt4][i] + bias;
                    acts[lrow][col] = f2b(fmaxf(v, 0.f));
                }
        }
        __syncthreads();

        // C1: relations = relu1_r[64x128] @ rw2 + rb2
        {
            f32x4 rc[4];
#pragma unroll
            for (int rt = 0; rt < 4; rt++) rc[rt] = (f32x4)(0.f);
#pragma unroll
            for (int ks = 0; ks < 4; ks++) {
                bf16x8 bfr = *(const bf16x8*)(rw2T + (w * 16 + ln) * 128 +
                                              ks * 32 + q * 8);
#pragma unroll
                for (int rt = 0; rt < 4; rt++) {
                    bf16x8 afr = *(const bf16x8*)&acts[rt * 16 + ln][192 + ks * 32 + q * 8];
                    rc[rt] = __builtin_amdgcn_mfma_f32_16x16x32_bf16(afr, bfr, rc[rt], 0, 0, 0);
                }
            }
            int col = w * 16 + ln;
            float bias = rb2[col];
            float* rel = out + 2 * (size_t)N;
#pragma unroll
            for (int rt = 0; rt < 4; rt++)
#pragma unroll
                for (int i = 0; i < 4; i++) {
                    int grow = r0 + h * 64 + rt * 16 + q * 4 + i;
                    rel[(size_t)grow * 64 + col] = rc[rt][i] + bias;
                }
        }

        // C2: h2 = relu(relu1_p[64x128] @ pw2 + pb2) -> h2s
        {
            f32x4 pc[4];
#pragma unroll
            for (int rt = 0; rt < 4; rt++) pc[rt] = (f32x4)(0.f);
#pragma unroll
            for (int ks = 0; ks < 4; ks++) {
                bf16x8 bfr = *(const bf16x8*)(pw2T + (w * 16 + ln) * 128 +
                                              ks * 32 + q * 8);
#pragma unroll
                for (int rt = 0; rt < 4; rt++) {
                    bf16x8 afr = *(const bf16x8*)&acts[rt * 16 + ln][0 + ks * 32 + q * 8];
                    pc[rt] = __builtin_amdgcn_mfma_f32_16x16x32_bf16(afr, bfr, pc[rt], 0, 0, 0);
                }
            }
            int col = w * 16 + ln;
            float bias = pb2[col];
#pragma unroll
            for (int rt = 0; rt < 4; rt++)
#pragma unroll
                for (int i = 0; i < 4; i++) {
                    int lrow = rt * 16 + q * 4 + i;
                    h2s[lrow][col] = f2b(fmaxf(pc[rt][i] + bias, 0.f));
                }
        }
        __syncthreads();

        // C3: probs; C4: directions
        if (t < 64) {
            float s = pb3[0];
#pragma unroll 8
            for (int k = 0; k < 64; k++) s += b2f(h2s[t][k]) * pw3[k];
            float pr = 1.f / (1.f + __expf(-s));
            out[r0 + h * 64 + t] = pr;
        } else if (t < 128) {
            int lrow = t - 64;
            float s = db2[0];
#pragma unroll 8
            for (int k = 0; k < 64; k++) s += b2f(acts[lrow][128 + k]) * dw2[k];
            float dir = (1.f / (1.f + __expf(-s))) * 1.57079632679489662f;
            out[(size_t)N + r0 + h * 64 + lrow] = dir;
        }
        __syncthreads();   // protect acts/h2s before next half overwrites
    }
}

extern "C" void kernel_launch(void* const* d_in, const int* in_sizes, int n_in,
                              void* d_out, int out_size, void* d_ws, size_t ws_size,
                              hipStream_t stream) {
    const float* beliefs = (const float*)d_in[0];
    const int* src = (const int*)d_in[1];
    const int* tgt = (const int*)d_in[2];
    const float* pw1 = (const float*)d_in[3];
    const float* pb1 = (const float*)d_in[4];
    const float* pw2 = (const float*)d_in[5];
    const float* pb2 = (const float*)d_in[6];
    const float* pw3 = (const float*)d_in[7];
    const float* pb3 = (const float*)d_in[8];
    const float* dw1 = (const float*)d_in[9];
    const float* db1 = (const float*)d_in[10];
    const float* dw2 = (const float*)d_in[11];
    const float* db2 = (const float*)d_in[12];
    const float* rw1 = (const float*)d_in[13];
    const float* rb1 = (const float*)d_in[14];
    const float* rw2 = (const float*)d_in[15];
    const float* rb2 = (const float*)d_in[16];

    short* ws = (short*)d_ws;
    short* WT    = ws;
    short* pw2T  = ws + P2T_OFF;
    short* rw2T  = ws + R2T_OFF;
    short* bel16 = ws + BEL_OFF;
    const int N = in_sizes[1];

    const bool useBf = ws_size >= (size_t)(PREP_TOT + BEL_ELEMS) * sizeof(short);
    const int prepElems = useBf ? (PREP_TOT + BEL_ELEMS) : PREP_TOT;

    prep_kernel<<<(prepElems + 255) / 256, 256, 0, stream>>>(
        pw1, dw1, rw1, pw2, rw2, beliefs, ws, prepElems);

    if (useBf)
        edge_main<true><<<N / ROWS, 256, 0, stream>>>(
            beliefs, bel16, src, tgt, pb1, db1, rb1, pb2, pw3, pb3,
            dw2, db2, rb2, WT, pw2T, rw2T, (float*)d_out, N);
    else
        edge_main<false><<<N / ROWS, 256, 0, stream>>>(
            beliefs, bel16, src, tgt, pb1, db1, rb1, pb2, pw3, pb3,
            dw2, db2, rb2, WT, pw2T, rw2T, (float*)d_out, N);
}

// Round 6
// 277.775 us; speedup vs baseline: 1.4866x; 1.4866x over previous
//
#include <hip/hip_runtime.h>
#include <hip/hip_bf16.h>

// EdgeProposer: probs/directions/relations heads over gathered belief pairs.
// f32 in / f32 out. R5 (128-row) spilled: 160 acc + 32 prefetch + 32 af
// regs > 256 budget -> 488MB scratch traffic. R6 keeps 128 rows but fits
// the register budget: no cross-k0 prefetch regs, B-outer inner loop
// (bfr[5] live = 20 regs, af transient 4-8). Live set ~210 < 256.

#define DD 512
#define K3 1536
#define ROWS 128
#define LDACT 328   // 320 + 8 pad
#define LDH 72

typedef short bf16x8 __attribute__((ext_vector_type(8)));
typedef float f32x4 __attribute__((ext_vector_type(4)));

__device__ inline float b2f(short s) {
    union { float f; unsigned u; } v;
    v.u = ((unsigned)(unsigned short)s) << 16;
    return v.f;
}
__device__ inline short f2b(float f) {   // RNE
    union { float fl; unsigned u; } v;
    v.fl = f;
    unsigned x = v.u;
    unsigned r = x + 0x7fffu + ((x >> 16) & 1u);
    return (short)(r >> 16);
}
__device__ inline short babsdiff(short a, short b) {
    union { float f; unsigned u; } v;
    v.f = b2f(a) - b2f(b);
    return (short)((v.u & 0x7fffffffu) >> 16);
}

// As2 fragment-major index: [seg][kk2][rt][lane][8] (shorts)
__device__ __forceinline__ int sidx(int seg, int kk2, int rt, int lane) {
    return (((seg * 2 + kk2) * 8 + rt) * 64 + lane) * 8;
}

// ---- workspace layout (shorts) ----
#define WT_ELEMS (320 * 1536)
#define P2T_OFF WT_ELEMS
#define R2T_OFF (WT_ELEMS + 64 * 128)
#define PREP_TOT (WT_ELEMS + 2 * 64 * 128)
#define BEL_ELEMS (8192 * 512)
#define BEL_OFF PREP_TOT

__global__ void prep_kernel(const float* __restrict__ pw1,
                            const float* __restrict__ dw1,
                            const float* __restrict__ rw1,
                            const float* __restrict__ pw2,
                            const float* __restrict__ rw2,
                            const float* __restrict__ beliefs,
                            short* __restrict__ ws, int total) {
    int i = blockIdx.x * 256 + threadIdx.x;
    if (i >= total) return;
    if (i < WT_ELEMS) {
        int n = i / K3, k = i - n * K3;
        float v;
        if (n < 128)      v = pw1[k * 128 + n];
        else if (n < 192) v = dw1[k * 64 + (n - 128)];
        else              v = rw1[k * 128 + (n - 192)];
        ws[i] = f2b(v);
    } else if (i < R2T_OFF) {
        int j = i - P2T_OFF;
        int n = j >> 7, k = j & 127;
        ws[i] = f2b(pw2[k * 64 + n]);
    } else if (i < PREP_TOT) {
        int j = i - R2T_OFF;
        int n = j >> 7, k = j & 127;
        ws[i] = f2b(rw2[k * 64 + n]);
    } else {
        ws[i] = f2b(beliefs[i - BEL_OFF]);
    }
}

// ---- main fused kernel: 128 pairs per block, 256 threads (4 waves) ----
template<bool BF>
__global__ __launch_bounds__(256, 2) void edge_main(
    const float* __restrict__ beliefs, const short* __restrict__ bel16,
    const int* __restrict__ src_idx, const int* __restrict__ tgt_idx,
    const float* __restrict__ pb1, const float* __restrict__ db1,
    const float* __restrict__ rb1,
    const float* __restrict__ pb2, const float* __restrict__ pw3,
    const float* __restrict__ pb3,
    const float* __restrict__ dw2, const float* __restrict__ db2,
    const float* __restrict__ rb2,
    const short* __restrict__ WT, const short* __restrict__ pw2T,
    const short* __restrict__ rw2T,
    float* __restrict__ out, int N)
{
    // As2 (K-loop, 48 KB) and acts (epilogue, 41 KB) alias
    __shared__ __align__(16) char smem_u[49152];
    __shared__ __align__(16) short h2s[64][LDH];            // 9216 B
    __shared__ int sIdx[ROWS], tIdx[ROWS];

    short* As2 = (short*)smem_u;
    short (*acts)[LDACT] = (short (*)[LDACT])smem_u;

    const int t = threadIdx.x;
    const int r0 = blockIdx.x * ROWS;
    const int w = t >> 6, lane = t & 63, q = lane >> 4, ln = lane & 15;

    if (t < ROWS) sIdx[t] = src_idx[r0 + t] * DD;
    else tIdx[t - ROWS] = tgt_idx[r0 + t - ROWS] * DD;
    __syncthreads();

    f32x4 acc[5][8];
#pragma unroll
    for (int ct = 0; ct < 5; ct++)
#pragma unroll
        for (int rt = 0; rt < 8; rt++) acc[ct][rt] = (f32x4)(0.f);

    // staging role: thread pair (t, t^1) covers one row; kk2w = 32-k half.
    const int rrow = t >> 1, kk2w = t & 1;
    const int rtw = rrow >> 4, lnw = rrow & 15;
    const int cb32 = kk2w * 32;
    const int srow = sIdx[rrow], trow = tIdx[rrow];

    for (int k0 = 0; k0 < DD; k0 += 64) {
        // ---- gather + cvt + stage (loads transient, not live across MFMA)
        if constexpr (BF) {
            const bf16x8* ps_ = (const bf16x8*)(bel16 + srow + k0 + cb32);
            const bf16x8* pt_ = (const bf16x8*)(bel16 + trow + k0 + cb32);
#pragma unroll
            for (int c = 0; c < 4; c++) {
                bf16x8 s8 = ps_[c], t8 = pt_[c], pa;
#pragma unroll
                for (int j = 0; j < 8; j++) pa[j] = babsdiff(s8[j], t8[j]);
                int l16 = c * 16 + lnw;
                *(bf16x8*)&As2[sidx(0, kk2w, rtw, l16)] = s8;
                *(bf16x8*)&As2[sidx(1, kk2w, rtw, l16)] = t8;
                *(bf16x8*)&As2[sidx(2, kk2w, rtw, l16)] = pa;
            }
        } else {
            const float4* ps_ = (const float4*)(beliefs + srow + k0 + cb32);
            const float4* pt_ = (const float4*)(beliefs + trow + k0 + cb32);
#pragma unroll
            for (int c = 0; c < 4; c++) {
                bf16x8 sb, tb, ab;
#pragma unroll
                for (int h = 0; h < 2; h++) {
                    float4 s4 = ps_[c * 2 + h], t4 = pt_[c * 2 + h];
                    float ss[4] = {s4.x, s4.y, s4.z, s4.w};
                    float tt[4] = {t4.x, t4.y, t4.z, t4.w};
#pragma unroll
                    for (int e = 0; e < 4; e++) {
                        int j = h * 4 + e;
                        sb[j] = f2b(ss[e]);
                        tb[j] = f2b(tt[e]);
                        ab[j] = f2b(fabsf(ss[e] - tt[e]));
                    }
                }
                int l16 = c * 16 + lnw;
                *(bf16x8*)&As2[sidx(0, kk2w, rtw, l16)] = sb;
                *(bf16x8*)&As2[sidx(1, kk2w, rtw, l16)] = tb;
                *(bf16x8*)&As2[sidx(2, kk2w, rtw, l16)] = ab;
            }
        }
        __syncthreads();

        // ---- MFMA phase, B-outer: bfr[5] (20 regs) live, af transient ----
#pragma unroll
        for (int kk2 = 0; kk2 < 2; kk2++) {
#pragma unroll
            for (int seg = 0; seg < 3; seg++) {
                bf16x8 bfr[5];
#pragma unroll
                for (int ct = 0; ct < 5; ct++) {
                    int col = w * 80 + ct * 16 + ln;
                    bfr[ct] = *(const bf16x8*)(WT + (size_t)col * K3 +
                                               seg * DD + k0 + kk2 * 32 + q * 8);
                }
#pragma unroll
                for (int rt = 0; rt < 8; rt++) {
                    bf16x8 af = *(const bf16x8*)&As2[sidx(seg, kk2, rt, lane)];
#pragma unroll
                    for (int ct = 0; ct < 5; ct++)
                        acc[ct][rt] = __builtin_amdgcn_mfma_f32_16x16x32_bf16(
                            af, bfr[ct], acc[ct][rt], 0, 0, 0);
                }
            }
        }
        __syncthreads();
    }

    // ---- epilogue: two 64-row halves ----
#pragma unroll
    for (int h = 0; h < 2; h++) {
        // phase B: bias + relu -> acts[64][320]. C/D: col=lane&15, row=q*4+reg.
#pragma unroll
        for (int ct = 0; ct < 5; ct++) {
            int col = w * 80 + ct * 16 + ln;
            float bias = (col < 128) ? pb1[col]
                       : (col < 192) ? db1[col - 128]
                                     : rb1[col - 192];
#pragma unroll
            for (int rt4 = 0; rt4 < 4; rt4++)
#pragma unroll
                for (int i = 0; i < 4; i++) {
                    int lrow = rt4 * 16 + q * 4 + i;
                    float v = acc[ct][h * 4 + rt4][i] + bias;
                    acts[lrow][col] = f2b(fmaxf(v, 0.f));
                }
        }
        __syncthreads();

        // C1: relations = relu1_r[64x128] @ rw2 + rb2
        {
            f32x4 rc[4];
#pragma unroll
            for (int rt = 0; rt < 4; rt++) rc[rt] = (f32x4)(0.f);
#pragma unroll
            for (int ks = 0; ks < 4; ks++) {
                bf16x8 bfr = *(const bf16x8*)(rw2T + (w * 16 + ln) * 128 +
                                              ks * 32 + q * 8);
#pragma unroll
                for (int rt = 0; rt < 4; rt++) {
                    bf16x8 afr = *(const bf16x8*)&acts[rt * 16 + ln][192 + ks * 32 + q * 8];
                    rc[rt] = __builtin_amdgcn_mfma_f32_16x16x32_bf16(afr, bfr, rc[rt], 0, 0, 0);
                }
            }
            int col = w * 16 + ln;
            float bias = rb2[col];
            float* rel = out + 2 * (size_t)N;
#pragma unroll
            for (int rt = 0; rt < 4; rt++)
#pragma unroll
                for (int i = 0; i < 4; i++) {
                    int grow = r0 + h * 64 + rt * 16 + q * 4 + i;
                    rel[(size_t)grow * 64 + col] = rc[rt][i] + bias;
                }
        }

        // C2: h2 = relu(relu1_p[64x128] @ pw2 + pb2) -> h2s
        {
            f32x4 pc[4];
#pragma unroll
            for (int rt = 0; rt < 4; rt++) pc[rt] = (f32x4)(0.f);
#pragma unroll
            for (int ks = 0; ks < 4; ks++) {
                bf16x8 bfr = *(const bf16x8*)(pw2T + (w * 16 + ln) * 128 +
                                              ks * 32 + q * 8);
#pragma unroll
                for (int rt = 0; rt < 4; rt++) {
                    bf16x8 afr = *(const bf16x8*)&acts[rt * 16 + ln][0 + ks * 32 + q * 8];
                    pc[rt] = __builtin_amdgcn_mfma_f32_16x16x32_bf16(afr, bfr, pc[rt], 0, 0, 0);
                }
            }
            int col = w * 16 + ln;
            float bias = pb2[col];
#pragma unroll
            for (int rt = 0; rt < 4; rt++)
#pragma unroll
                for (int i = 0; i < 4; i++) {
                    int lrow = rt * 16 + q * 4 + i;
                    h2s[lrow][col] = f2b(fmaxf(pc[rt][i] + bias, 0.f));
                }
        }
        __syncthreads();

        // C3: probs; C4: directions
        if (t < 64) {
            float s = pb3[0];
#pragma unroll 8
            for (int k = 0; k < 64; k++) s += b2f(h2s[t][k]) * pw3[k];
            float pr = 1.f / (1.f + __expf(-s));
            out[r0 + h * 64 + t] = pr;
        } else if (t < 128) {
            int lrow = t - 64;
            float s = db2[0];
#pragma unroll 8
            for (int k = 0; k < 64; k++) s += b2f(acts[lrow][128 + k]) * dw2[k];
            float dir = (1.f / (1.f + __expf(-s))) * 1.57079632679489662f;
            out[(size_t)N + r0 + h * 64 + lrow] = dir;
        }
        __syncthreads();   // protect acts/h2s before next half overwrites
    }
}

extern "C" void kernel_launch(void* const* d_in, const int* in_sizes, int n_in,
                              void* d_out, int out_size, void* d_ws, size_t ws_size,
                              hipStream_t stream) {
    const float* beliefs = (const float*)d_in[0];
    const int* src = (const int*)d_in[1];
    const int* tgt = (const int*)d_in[2];
    const float* pw1 = (const float*)d_in[3];
    const float* pb1 = (const float*)d_in[4];
    const float* pw2 = (const float*)d_in[5];
    const float* pb2 = (const float*)d_in[6];
    const float* pw3 = (const float*)d_in[7];
    const float* pb3 = (const float*)d_in[8];
    const float* dw1 = (const float*)d_in[9];
    const float* db1 = (const float*)d_in[10];
    const float* dw2 = (const float*)d_in[11];
    const float* db2 = (const float*)d_in[12];
    const float* rw1 = (const float*)d_in[13];
    const float* rb1 = (const float*)d_in[14];
    const float* rw2 = (const float*)d_in[15];
    const float* rb2 = (const float*)d_in[16];

    short* ws = (short*)d_ws;
    short* WT    = ws;
    short* pw2T  = ws + P2T_OFF;
    short* rw2T  = ws + R2T_OFF;
    short* bel16 = ws + BEL_OFF;
    const int N = in_sizes[1];

    const bool useBf = ws_size >= (size_t)(PREP_TOT + BEL_ELEMS) * sizeof(short);
    const int prepElems = useBf ? (PREP_TOT + BEL_ELEMS) : PREP_TOT;

    prep_kernel<<<(prepElems + 255) / 256, 256, 0, stream>>>(
        pw1, dw1, rw1, pw2, rw2, beliefs, ws, prepElems);

    if (useBf)
        edge_main<true><<<N / ROWS, 256, 0, stream>>>(
            beliefs, bel16, src, tgt, pb1, db1, rb1, pb2, pw3, pb3,
            dw2, db2, rb2, WT, pw2T, rw2T, (float*)d_out, N);
    else
        edge_main<false><<<N / ROWS, 256, 0, stream>>>(
            beliefs, bel16, src, tgt, pb1, db1, rb1, pb2, pw3, pb3,
            dw2, db2, rb2, WT, pw2T, rw2T, (float*)d_out, N);
}